// Round 1
// baseline (4183.355 us; speedup 1.0000x reference)
//
#include <hip/hip_runtime.h>
#include <math.h>

#define TT 32      // time length
#define MM 16      // kept modes
#define CC 128     // in = out channels
#define NPT 32768  // spatial points
#define BN 8       // n-points per block
#define XST 36     // padded floats per (nn,i) column in LDS (bank-conflict pad, 16B aligned)

// Dynamic LDS layout:
//   float xf[BN*CC*XST]   : XF[nn][i][m][ri] real/imag interleaved, stride XST per (nn,i)
//   float tabc[512]       : cos(2*pi*m*t/32), index m*32+t
//   float tabs[512]       : sin(2*pi*m*t/32)
__global__ __launch_bounds__(512, 2)
void spectral_fused(const float* __restrict__ x,
                    const float* __restrict__ w,
                    float* __restrict__ out) {
    extern __shared__ float lds[];
    float* xf   = lds;                  // 36864 floats
    float* tabc = lds + BN * CC * XST;  // 512 floats
    float* tabs = tabc + 512;           // 512 floats

    const int tid = threadIdx.x;
    const int n0  = blockIdx.x * BN;

    // ---------- phase 0: fill cos/sin tables ----------
    {
        const int m = tid >> 5;
        const int t = tid & 31;
        const int k = (m * t) & 31;                     // angle mod 2*pi, exact in int
        const float ang = 0.19634954084936207f * (float)k;  // 2*pi/32
        float s, c;
        sincosf(ang, &s, &c);
        tabc[tid] = c;
        tabs[tid] = s;
    }
    __syncthreads();

    // ---------- phase 1: rfft (explicit DFT over t) ----------
    // thread handles columns (nnA, i) and (nnB, i); writes XF to LDS
    {
        const int i   = tid & 127;
        const int nnA = tid >> 7;      // 0..3
        const int nnB = nnA + 4;       // 4..7
        float xra[MM], xia[MM], xrb[MM], xib[MM];
        #pragma unroll
        for (int m = 0; m < MM; ++m) { xra[m]=0.f; xia[m]=0.f; xrb[m]=0.f; xib[m]=0.f; }

        const float* xA = x + (size_t)(n0 + nnA) * CC + i;
        const float* xB = x + (size_t)(n0 + nnB) * CC + i;
        for (int t = 0; t < TT; ++t) {
            const float va = xA[(size_t)t * NPT * CC];
            const float vb = xB[(size_t)t * NPT * CC];
            #pragma unroll
            for (int m = 0; m < MM; ++m) {
                const float c = tabc[(m << 5) + t];
                const float s = tabs[(m << 5) + t];
                xra[m] += va * c;  xia[m] -= va * s;   // rfft: e^{-i 2pi m t / T}
                xrb[m] += vb * c;  xib[m] -= vb * s;
            }
        }
        float* dA = xf + (size_t)(nnA * CC + i) * XST;
        float* dB = xf + (size_t)(nnB * CC + i) * XST;
        #pragma unroll
        for (int j = 0; j < 8; ++j) {
            *(float4*)(dA + 4 * j) = make_float4(xra[2*j], xia[2*j], xra[2*j+1], xia[2*j+1]);
            *(float4*)(dB + 4 * j) = make_float4(xrb[2*j], xib[2*j], xrb[2*j+1], xib[2*j+1]);
        }
    }
    __syncthreads();

    // ---------- phase 2: per-mode complex einsum over i ----------
    // thread owns output pairs (nnA, o) and (nnB, o); accumulators OF[m] complex
    const int o   = tid & 127;
    const int nnA = tid >> 7;
    const int nnB = nnA + 4;
    float ar[MM], ai_[MM], br[MM], bi_[MM];
    #pragma unroll
    for (int m = 0; m < MM; ++m) { ar[m]=0.f; ai_[m]=0.f; br[m]=0.f; bi_[m]=0.f; }

    const float* qa0 = xf + (size_t)(nnA * CC) * XST;
    const float* qb0 = xf + (size_t)(nnB * CC) * XST;

    // weights layout: w[i][o][m][ri] -> for fixed (i,o): 32 contiguous floats
    float4 wv[8];
    {
        const float4* wp = (const float4*)(w + (size_t)o * 32);
        #pragma unroll
        for (int j = 0; j < 8; ++j) wv[j] = wp[j];
    }
    for (int i = 0; i < CC; ++i) {
        float4 xa4[8], xb4[8];
        const float4* qa = (const float4*)(qa0 + i * XST);
        const float4* qb = (const float4*)(qb0 + i * XST);
        #pragma unroll
        for (int j = 0; j < 8; ++j) { xa4[j] = qa[j]; xb4[j] = qb[j]; }

        float4 wn[8];                           // prefetch next i's weights
        if (i + 1 < CC) {
            const float4* wp = (const float4*)(w + (size_t)((i + 1) * CC + o) * 32);
            #pragma unroll
            for (int j = 0; j < 8; ++j) wn[j] = wp[j];
        }

        #pragma unroll
        for (int j = 0; j < 8; ++j) {
            const int m0 = 2 * j, m1 = 2 * j + 1;
            // pair A, mode m0: (Xr+iXi)*(Wr+iWi)
            ar[m0]  += xa4[j].x * wv[j].x - xa4[j].y * wv[j].y;
            ai_[m0] += xa4[j].x * wv[j].y + xa4[j].y * wv[j].x;
            br[m0]  += xb4[j].x * wv[j].x - xb4[j].y * wv[j].y;
            bi_[m0] += xb4[j].x * wv[j].y + xb4[j].y * wv[j].x;
            ar[m1]  += xa4[j].z * wv[j].z - xa4[j].w * wv[j].w;
            ai_[m1] += xa4[j].z * wv[j].w + xa4[j].w * wv[j].z;
            br[m1]  += xb4[j].z * wv[j].z - xb4[j].w * wv[j].w;
            bi_[m1] += xb4[j].z * wv[j].w + xb4[j].w * wv[j].z;
        }
        #pragma unroll
        for (int j = 0; j < 8; ++j) wv[j] = wn[j];
    }

    // ---------- phase 3: irfft epilogue ----------
    // out[t] = (1/32) * [ Re OF0 + 2 * sum_{m=1}^{15} (Re OFm cos - Im OFm sin) ]
    // (mode 16 is zero-padded by irfft(n=32); imag of mode 0 is ignored by c2r)
    {
        const float inv = 1.0f / 32.0f;
        const size_t obA = (size_t)(n0 + nnA) * CC + o;
        const size_t obB = (size_t)(n0 + nnB) * CC + o;
        for (int t = 0; t < TT; ++t) {
            float accA = 0.f, accB = 0.f;
            #pragma unroll
            for (int m = 1; m < MM; ++m) {
                const float c = tabc[(m << 5) + t];
                const float s = tabs[(m << 5) + t];
                accA += ar[m] * c - ai_[m] * s;
                accB += br[m] * c - bi_[m] * s;
            }
            out[(size_t)t * NPT * CC + obA] = (ar[0] + 2.f * accA) * inv;
            out[(size_t)t * NPT * CC + obB] = (br[0] + 2.f * accB) * inv;
        }
    }
}

extern "C" void kernel_launch(void* const* d_in, const int* in_sizes, int n_in,
                              void* d_out, int out_size, void* d_ws, size_t ws_size,
                              hipStream_t stream) {
    (void)in_sizes; (void)n_in; (void)out_size; (void)d_ws; (void)ws_size;
    const float* x = (const float*)d_in[0];
    const float* w = (const float*)d_in[1];
    float* out     = (float*)d_out;

    const size_t lds_bytes = (size_t)(BN * CC * XST + 1024) * sizeof(float);  // 151552 B
    hipLaunchKernelGGL(spectral_fused, dim3(NPT / BN), dim3(512), lds_bytes, stream,
                       x, w, out);
}

// Round 3
// 464.672 us; speedup vs baseline: 9.0028x; 9.0028x over previous
//
#include <hip/hip_runtime.h>
#include <math.h>

typedef short bf16x8 __attribute__((ext_vector_type(8)));
typedef float f32x4  __attribute__((ext_vector_type(4)));

#define TT 32
#define MM 16
#define CC 128
#define NPT 32768
#define NC 4194304          // NPT*CC, elements per time-slice
#define BN 16               // n-points per block (main kernel)

// ---- LDS layout (bytes) for main kernel ----
// XF: bf16 [m16][n16][i128][ri2] = 131072 B, phys = L ^ ((n&7)<<4) (full-addr XOR)
// OF: bf16 [no256][k2_32] with PADDED row stride 80 B = 20480 B (no swizzle)
// DT: bf16 [t32][k2_32] = 2048 B ; TABC/TABS: f32 [t32][m16] = 2048 B each
#define XF_OFF   0
#define OF_OFF   131072
#define OF_STRIDE 80
#define DT_OFF   151552
#define TABC_OFF 153600
#define TABS_OFF 155648
#define LDS_BYTES 157696

static __device__ __forceinline__ unsigned short f2bf(float f) {
    union { float f; unsigned u; } v; v.f = f;
    unsigned r = v.u + 0x7FFFu + ((v.u >> 16) & 1u);   // RNE
    return (unsigned short)(r >> 16);
}

// ============================================================================
// Weight repack: w[i][o][m][ri] f32  ->  bf16 MFMA B-fragments in d_ws.
// Layout (short8 rows): WB[m][riOut][ck][ot][lane]  (16*2*8*8*64 rows).
// Row holds B[k = ck*32 + (lane>>4)*8 + j][o = ot*16 + (lane&15)], j=0..7,
// where k = 2i+ri_in stacking:  B_R = {+Wr, -Wi},  B_I = {+Wi, +Wr}.
// ============================================================================
__global__ void repack_w(const float* __restrict__ w, bf16x8* __restrict__ wb) {
    int r = blockIdx.x * blockDim.x + threadIdx.x;    // 0..131071
    int lane = r & 63;
    int r2 = r >> 6;
    int ot = r2 & 7;
    int r3 = r2 >> 3;
    int ck = r3 & 7;
    int r4 = r3 >> 3;
    int ri = r4 & 1;
    int m  = r4 >> 1;
    int o = ot * 16 + (lane & 15);
    int kbase = ck * 32 + (lane >> 4) * 8;
    bf16x8 v;
    #pragma unroll
    for (int j = 0; j < 8; ++j) {
        int k = kbase + j;
        int i = k >> 1, ko = k & 1;
        const float* wp = w + ((size_t)(i * 128 + o) * 16 + m) * 2;
        float val;
        if (ri == 0) val = ko ? -wp[1] : wp[0];
        else         val = ko ?  wp[0] : wp[1];
        v[j] = (short)f2bf(val);
    }
    wb[r] = v;
}

// ============================================================================
// Main fused kernel: 1024 threads = 16 waves; wave w = mode w (einsum phase)
// and n-row w (irfft phase). BN=16 n-points per block.
// ============================================================================
__global__ __launch_bounds__(1024, 2)
void spectral_mfma(const float* __restrict__ x, const bf16x8* __restrict__ wb,
                   float* __restrict__ out) {
    extern __shared__ char lds[];
    float* tabc = (float*)(lds + TABC_OFF);
    float* tabs = (float*)(lds + TABS_OFF);
    const int tid = threadIdx.x;
    const int n0  = blockIdx.x * BN;

    // ---------- phase 0: tables ----------
    if (tid < 512) {                       // rfft tables, transposed [t][m]
        int m = tid & 15, t = tid >> 4;    // t 0..31
        float ang = 0.19634954084936207f * (float)((m * t) & 31);
        float s, c; sincosf(ang, &s, &c);
        tabc[t * 16 + m] = c;
        tabs[t * 16 + m] = s;
    }
    {                                      // irfft matrix DT[t][2m+ri] bf16
        int t = tid >> 5, k2 = tid & 31, m = k2 >> 1, ri = k2 & 1;
        float alpha = (m == 0) ? 0.03125f : 0.0625f;   // 1/32, 2/32
        float ang = 0.19634954084936207f * (float)((m * t) & 31);
        float s, c; sincosf(ang, &s, &c);
        float val = (ri == 0) ? alpha * c : -alpha * s;
        if (m == 0 && ri == 1) val = 0.f;  // c2r ignores imag of bin 0
        *(unsigned short*)(lds + DT_OFF + t * 64 + k2 * 2) = f2bf(val);
    }
    __syncthreads();

    // ---------- phase 1: folded rfft, XF -> LDS bf16 ----------
    {
        const int i2 = (tid & 63) * 2;     // two adjacent i-columns
        const int nn = tid >> 6;           // 0..15
        const float* xp = x + (size_t)(n0 + nn) * CC + i2;
        float2 x0  = *(const float2*)(xp);
        float2 x16 = *(const float2*)(xp + (size_t)16 * NC);
        float xrA[16], xiA[16], xrB[16], xiB[16];
        #pragma unroll
        for (int m = 0; m < 16; ++m) {
            float sgn = (m & 1) ? -1.f : 1.f;
            xrA[m] = x0.x + sgn * x16.x;
            xrB[m] = x0.y + sgn * x16.y;
            xiA[m] = 0.f; xiB[m] = 0.f;
        }
        #pragma unroll 3
        for (int t = 1; t <= 15; ++t) {
            float2 a = *(const float2*)(xp + (size_t)t * NC);
            float2 b = *(const float2*)(xp + (size_t)(32 - t) * NC);
            float ex = a.x + b.x, ey = a.y + b.y;
            float ox = a.x - b.x, oy = a.y - b.y;
            float4 c0 = *(const float4*)&tabc[t * 16 + 0];
            float4 c1 = *(const float4*)&tabc[t * 16 + 4];
            float4 c2 = *(const float4*)&tabc[t * 16 + 8];
            float4 c3 = *(const float4*)&tabc[t * 16 + 12];
            float4 s0 = *(const float4*)&tabs[t * 16 + 0];
            float4 s1 = *(const float4*)&tabs[t * 16 + 4];
            float4 s2 = *(const float4*)&tabs[t * 16 + 8];
            float4 s3 = *(const float4*)&tabs[t * 16 + 12];
            float cm[16] = {c0.x,c0.y,c0.z,c0.w, c1.x,c1.y,c1.z,c1.w,
                            c2.x,c2.y,c2.z,c2.w, c3.x,c3.y,c3.z,c3.w};
            float sm[16] = {s0.x,s0.y,s0.z,s0.w, s1.x,s1.y,s1.z,s1.w,
                            s2.x,s2.y,s2.z,s2.w, s3.x,s3.y,s3.z,s3.w};
            #pragma unroll
            for (int m = 0; m < 16; ++m) {
                xrA[m] += ex * cm[m]; xrB[m] += ey * cm[m];
                xiA[m] -= ox * sm[m]; xiB[m] -= oy * sm[m];
            }
        }
        char* xfb = lds + XF_OFF;
        #pragma unroll
        for (int m = 0; m < 16; ++m) {
            unsigned byte = (unsigned)(m * 8192 + nn * 512 + i2 * 4);
            byte ^= (unsigned)((nn & 7) << 4);
            uint2 v;
            v.x = (unsigned)f2bf(xrA[m]) | ((unsigned)f2bf(xiA[m]) << 16);
            v.y = (unsigned)f2bf(xrB[m]) | ((unsigned)f2bf(xiB[m]) << 16);
            *(uint2*)(xfb + byte) = v;
        }
    }
    __syncthreads();

    // ---------- phase 2/3: einsum MFMA + irfft MFMA, per 16-wide o-tile ----------
    const int lane = tid & 63;
    const int wid  = tid >> 6;     // einsum: mode; irfft: n-row
    const int col  = lane & 15;
    const int kq   = lane >> 4;

    // hoisted A-fragments: XF[mode=wid] rows n=col, k = ck*32 + kq*8 + j.
    // NOTE: XOR swizzle applied to the FULL logical address (matches write map).
    bf16x8 afrag[8];
    {
        char* xfb = lds + XF_OFF;
        const unsigned row = (unsigned)(wid * 8192 + col * 512 + kq * 16);
        const unsigned swz = (unsigned)((col & 7) << 4);
        #pragma unroll
        for (int ck = 0; ck < 8; ++ck) {
            unsigned addr = (row + (unsigned)(ck * 64)) ^ swz;
            afrag[ck] = *(const bf16x8*)(xfb + addr);
        }
    }
    // hoisted irfft A-fragments: DT rows t=col (+16), k2 = kq*8 + j
    bf16x8 dtf0, dtf1;
    {
        char* dtb = lds + DT_OFF;
        dtf0 = *(const bf16x8*)(dtb + col * 64 + kq * 16);
        dtf1 = *(const bf16x8*)(dtb + (col + 16) * 64 + kq * 16);
    }

    char* ofb = lds + OF_OFF;
    float* outp = out + (size_t)(n0 + wid) * CC + col;

    for (int og = 0; og < 8; ++og) {
        // --- einsum: OF[mode=wid] for o-tile og, K=256 over (i,ri) ---
        f32x4 accR = {0.f, 0.f, 0.f, 0.f};
        f32x4 accI = {0.f, 0.f, 0.f, 0.f};
        #pragma unroll
        for (int ck = 0; ck < 8; ++ck) {
            bf16x8 bR = wb[(((wid * 2 + 0) * 8 + ck) * 8 + og) * 64 + lane];
            bf16x8 bI = wb[(((wid * 2 + 1) * 8 + ck) * 8 + og) * 64 + lane];
            accR = __builtin_amdgcn_mfma_f32_16x16x32_bf16(afrag[ck], bR, accR, 0, 0, 0);
            accI = __builtin_amdgcn_mfma_f32_16x16x32_bf16(afrag[ck], bI, accI, 0, 0, 0);
        }
        // write C-frags (col=o, rows n=kq*4+j) into OF[no = n*16+o][2m+ri]
        #pragma unroll
        for (int j = 0; j < 4; ++j) {
            int no = (kq * 4 + j) * 16 + col;
            unsigned byte = (unsigned)(no * OF_STRIDE + wid * 4);
            unsigned v = (unsigned)f2bf(accR[j]) | ((unsigned)f2bf(accI[j]) << 16);
            *(unsigned*)(ofb + byte) = v;
        }
        __syncthreads();
        // --- irfft: out[t][no-chunk=wid] = DT x OF^T, then coalesced stores ---
        {
            int no0 = wid * 16 + col;
            bf16x8 pf = *(const bf16x8*)(ofb + no0 * OF_STRIDE + kq * 16);
            f32x4 z = {0.f, 0.f, 0.f, 0.f};
            f32x4 c0 = __builtin_amdgcn_mfma_f32_16x16x32_bf16(dtf0, pf, z, 0, 0, 0);
            f32x4 c1 = __builtin_amdgcn_mfma_f32_16x16x32_bf16(dtf1, pf, z, 0, 0, 0);
            float* op = outp + og * 16;
            #pragma unroll
            for (int j = 0; j < 4; ++j) {
                int t0 = kq * 4 + j;
                op[(size_t)t0 * NC]        = c0[j];
                op[(size_t)(t0 + 16) * NC] = c1[j];
            }
        }
        __syncthreads();   // OF reused next og
    }
}

// ============================================================================
// Fallback (round-1 proven kernel) — used only if ws_size < 2 MB.
// ============================================================================
#define FBN 8
#define FXST 36
__global__ __launch_bounds__(512, 2)
void spectral_fused(const float* __restrict__ x,
                    const float* __restrict__ w,
                    float* __restrict__ out) {
    extern __shared__ float flds[];
    float* xf    = flds;
    float* ftabc = flds + FBN * CC * FXST;
    float* ftabs = ftabc + 512;

    const int tid = threadIdx.x;
    const int n0  = blockIdx.x * FBN;

    {
        const int m = tid >> 5;
        const int t = tid & 31;
        const int k = (m * t) & 31;
        const float ang = 0.19634954084936207f * (float)k;
        float s, c; sincosf(ang, &s, &c);
        ftabc[tid] = c; ftabs[tid] = s;
    }
    __syncthreads();
    {
        const int i   = tid & 127;
        const int nnA = tid >> 7;
        const int nnB = nnA + 4;
        float xra[MM], xia[MM], xrb[MM], xib[MM];
        #pragma unroll
        for (int m = 0; m < MM; ++m) { xra[m]=0.f; xia[m]=0.f; xrb[m]=0.f; xib[m]=0.f; }
        const float* xA = x + (size_t)(n0 + nnA) * CC + i;
        const float* xB = x + (size_t)(n0 + nnB) * CC + i;
        for (int t = 0; t < TT; ++t) {
            const float va = xA[(size_t)t * NC];
            const float vb = xB[(size_t)t * NC];
            #pragma unroll
            for (int m = 0; m < MM; ++m) {
                const float c = ftabc[(m << 5) + t];
                const float s = ftabs[(m << 5) + t];
                xra[m] += va * c;  xia[m] -= va * s;
                xrb[m] += vb * c;  xib[m] -= vb * s;
            }
        }
        float* dA = xf + (size_t)(nnA * CC + i) * FXST;
        float* dB = xf + (size_t)(nnB * CC + i) * FXST;
        #pragma unroll
        for (int j = 0; j < 8; ++j) {
            *(float4*)(dA + 4 * j) = make_float4(xra[2*j], xia[2*j], xra[2*j+1], xia[2*j+1]);
            *(float4*)(dB + 4 * j) = make_float4(xrb[2*j], xib[2*j], xrb[2*j+1], xib[2*j+1]);
        }
    }
    __syncthreads();
    const int o   = tid & 127;
    const int nnA = tid >> 7;
    const int nnB = nnA + 4;
    float ar[MM], ai_[MM], br[MM], bi_[MM];
    #pragma unroll
    for (int m = 0; m < MM; ++m) { ar[m]=0.f; ai_[m]=0.f; br[m]=0.f; bi_[m]=0.f; }
    const float* qa0 = xf + (size_t)(nnA * CC) * FXST;
    const float* qb0 = xf + (size_t)(nnB * CC) * FXST;
    float4 wv[8];
    {
        const float4* wp = (const float4*)(w + (size_t)o * 32);
        #pragma unroll
        for (int j = 0; j < 8; ++j) wv[j] = wp[j];
    }
    for (int i = 0; i < CC; ++i) {
        float4 xa4[8], xb4[8];
        const float4* qa = (const float4*)(qa0 + i * FXST);
        const float4* qb = (const float4*)(qb0 + i * FXST);
        #pragma unroll
        for (int j = 0; j < 8; ++j) { xa4[j] = qa[j]; xb4[j] = qb[j]; }
        float4 wn[8];
        if (i + 1 < CC) {
            const float4* wp = (const float4*)(w + (size_t)((i + 1) * CC + o) * 32);
            #pragma unroll
            for (int j = 0; j < 8; ++j) wn[j] = wp[j];
        }
        #pragma unroll
        for (int j = 0; j < 8; ++j) {
            const int m0 = 2 * j, m1 = 2 * j + 1;
            ar[m0]  += xa4[j].x * wv[j].x - xa4[j].y * wv[j].y;
            ai_[m0] += xa4[j].x * wv[j].y + xa4[j].y * wv[j].x;
            br[m0]  += xb4[j].x * wv[j].x - xb4[j].y * wv[j].y;
            bi_[m0] += xb4[j].x * wv[j].y + xb4[j].y * wv[j].x;
            ar[m1]  += xa4[j].z * wv[j].z - xa4[j].w * wv[j].w;
            ai_[m1] += xa4[j].z * wv[j].w + xa4[j].w * wv[j].z;
            br[m1]  += xb4[j].z * wv[j].z - xb4[j].w * wv[j].w;
            bi_[m1] += xb4[j].z * wv[j].w + xb4[j].w * wv[j].z;
        }
        #pragma unroll
        for (int j = 0; j < 8; ++j) wv[j] = wn[j];
    }
    {
        const float inv = 1.0f / 32.0f;
        const size_t obA = (size_t)(n0 + nnA) * CC + o;
        const size_t obB = (size_t)(n0 + nnB) * CC + o;
        for (int t = 0; t < TT; ++t) {
            float accA = 0.f, accB = 0.f;
            #pragma unroll
            for (int m = 1; m < MM; ++m) {
                const float c = ftabc[(m << 5) + t];
                const float s = ftabs[(m << 5) + t];
                accA += ar[m] * c - ai_[m] * s;
                accB += br[m] * c - bi_[m] * s;
            }
            out[(size_t)t * NC + obA] = (ar[0] + 2.f * accA) * inv;
            out[(size_t)t * NC + obB] = (br[0] + 2.f * accB) * inv;
        }
    }
}

extern "C" void kernel_launch(void* const* d_in, const int* in_sizes, int n_in,
                              void* d_out, int out_size, void* d_ws, size_t ws_size,
                              hipStream_t stream) {
    (void)in_sizes; (void)n_in; (void)out_size;
    const float* x = (const float*)d_in[0];
    const float* w = (const float*)d_in[1];
    float* out     = (float*)d_out;

    if (d_ws != nullptr && ws_size >= (size_t)2 * 1024 * 1024) {
        bf16x8* wbuf = (bf16x8*)d_ws;
        hipLaunchKernelGGL(repack_w, dim3(512), dim3(256), 0, stream, w, wbuf);
        hipLaunchKernelGGL(spectral_mfma, dim3(NPT / BN), dim3(1024), LDS_BYTES, stream,
                           x, wbuf, out);
    } else {
        const size_t lds_bytes = (size_t)(FBN * CC * FXST + 1024) * sizeof(float);
        hipLaunchKernelGGL(spectral_fused, dim3(NPT / FBN), dim3(512), lds_bytes, stream,
                           x, w, out);
    }
}